// Round 1
// 231.789 us; speedup vs baseline: 1.0252x; 1.0252x over previous
//
#include <hip/hip_runtime.h>
#include <hip/hip_fp16.h>

// SpatialTransformer3D: B=2, H=W=D=128, C=4.
// out[b,i,j,k,:] = trilinear sample of image[b] at c = t*grid, t in [0,1).
//
// R7: counters show nothing saturated (HBM 13%, VALU 14%, 0 LDS conflicts)
// -> latency/request-rate bound on divergent gathers. We are at the byte
// lower bound (4 x 16B windows = 64B/voxel = 8 corners fp16). Measured
// ~3.9 cy per lane-request vs ~1 cy/req TA service floor. Theory: queue
// starvation (only ~20 waves/CU x 4 in-flight gathers). Lever: 2 voxels
// per thread (same octant, different i-slab) -> 8 gathers + 2 trans loads
// in flight per lane. Octant q -> XCD q map kept (FETCH 287->55 MB in R4);
// each octant's sample region is only 2 MB fp16 -> fits per-XCD L2.

typedef float f4 __attribute__((ext_vector_type(4)));
typedef unsigned int u32;
typedef u32 u4v __attribute__((ext_vector_type(4), aligned(8)));

__device__ inline float2 h2f(u32 b) {
    __half2 h = __builtin_bit_cast(__half2, b);
    return __half22float2(h);
}

// ---- Pass 1: fp32 image -> fp16 copy in workspace (same layout) ----
__global__ __launch_bounds__(256) void cvt_kernel(
    const f4* __restrict__ img, uint2* __restrict__ himg)
{
    int idx = blockIdx.x * 256 + threadIdx.x;   // f4 index, 0 .. B*128^3-1
    f4 v = img[idx];
    __half2 lo = __floats2half2_rn(v.x, v.y);
    __half2 hi = __floats2half2_rn(v.z, v.w);
    himg[idx] = make_uint2(__builtin_bit_cast(u32, lo), __builtin_bit_cast(u32, hi));
}

// ---- Pass 2: main sample kernel (fp16 gathers, 2 voxels/thread) ----
__global__ __launch_bounds__(256) void st3d_h2_kernel(
    const u32* __restrict__ himg,      // (B,128,128,128,4) fp16
    const float* __restrict__ trans,   // (B,128,128,128,3) fp32
    f4* __restrict__ out)              // (B,128,128,128,4) fp32
{
    // octant q -> XCD q via blockIdx%8 round-robin
    int bid = blockIdx.x;
    int q   = bid & 7;
    int n   = bid >> 3;                     // 0..1023
    int b   = n >> 9;
    int mA  = ((n & 511) << 8) | threadIdx.x;   // 0..131071 (ip 0..31)
    int mB  = mA + (1 << 17);                   // second voxel (ip 32..63)

    int qi = (q >> 2) & 1;
    int qj = (q >> 1) & 1;
    int qk = q & 1;

    const float step = 2.0f / 127.0f;

    // ---- geometry + trans load (issued early, both voxels) ----
#define SETUP(S, mval)                                                     \
    int kp##S  = (mval) & 63;                                              \
    int jp##S  = ((mval) >> 6) & 63;                                       \
    int ip##S  = (mval) >> 12;                                             \
    int ipe##S = qi ? ip##S : (63 - ip##S);   /* center-outward sweep */   \
    int i##S   = (qi << 6) + ipe##S;                                       \
    int j##S   = (qj << 6) + jp##S;                                        \
    int k##S   = (qk << 6) + kp##S;                                        \
    int idx##S = (((b << 7) | i##S) << 14) | (j##S << 7) | k##S;           \
    const float* t##S = trans + (size_t)idx##S * 3;                        \
    float tx##S = __builtin_nontemporal_load(t##S + 0);                    \
    float ty##S = __builtin_nontemporal_load(t##S + 1);                    \
    float tz##S = __builtin_nontemporal_load(t##S + 2);

    SETUP(A, mA)
    SETUP(B, mB)

    // ---- coords, clips, gather issue (all 8 gathers in flight) ----
#define GATHER(S)                                                          \
    float gx##S = -1.0f + step * (float)j##S;                              \
    float gy##S = -1.0f + step * (float)i##S;                              \
    float gz##S = -1.0f + step * (float)k##S;                              \
    float x##S = (tx##S * gx##S + 1.0f) * 64.0f;                           \
    float y##S = (ty##S * gy##S + 1.0f) * 64.0f;                           \
    float z##S = (tz##S * gz##S + 1.0f) * 64.0f;                           \
    int x0##S = (int)floorf(x##S);                                         \
    int y0##S = (int)floorf(y##S);                                         \
    int z0##S = (int)floorf(z##S);                                         \
    int x1##S = min(max(x0##S + 1, 0), 127);                               \
    int y1##S = min(max(y0##S + 1, 0), 127);                               \
    int z1##S = min(max(z0##S + 1, 0), 127);                               \
    x0##S = min(max(x0##S, 0), 127);                                       \
    y0##S = min(max(y0##S, 0), 127);                                       \
    z0##S = min(max(z0##S, 0), 127);                                       \
    /* weights use CLIPPED upper corners (reference semantics) */          \
    float dx##S = (float)x1##S - x##S;                                     \
    float dy##S = (float)y1##S - y##S;                                     \
    float dz##S = (float)z1##S - z##S;                                     \
    int zb##S = min(z0##S, 126);        /* 16B window covers zb, zb+1 */   \
    int i0##S = z0##S - zb##S;          /* 0 normally; 1 when z0==127 */   \
    int i1##S = z1##S - zb##S;          /* 1 normally */                   \
    int bb##S  = b << 21;                                                  \
    int ry0##S = bb##S + (y0##S << 14);                                    \
    int ry1##S = bb##S + (y1##S << 14);                                    \
    int cx0##S = x0##S << 7;                                               \
    int cx1##S = x1##S << 7;                                               \
    u4v d0##S = *(const u4v*)(himg + (size_t)(ry0##S + cx0##S + zb##S) * 2); \
    u4v d1##S = *(const u4v*)(himg + (size_t)(ry1##S + cx0##S + zb##S) * 2); \
    u4v d2##S = *(const u4v*)(himg + (size_t)(ry0##S + cx1##S + zb##S) * 2); \
    u4v d3##S = *(const u4v*)(himg + (size_t)(ry1##S + cx1##S + zb##S) * 2);

    GATHER(A)
    GATHER(B)

    // per-pair (z0-weight, z1-weight); pairing matches reference terms
#define ACC1(d, wA, wB, ii0, ii1, ox, oy, oz, ow)                          \
    {                                                                      \
        u32 a0 = (ii0) ? (d).z : (d).x;  /* c0c1 @ z0 */                   \
        u32 a1 = (ii0) ? (d).w : (d).y;  /* c2c3 @ z0 */                   \
        u32 b0 = (ii1) ? (d).z : (d).x;  /* c0c1 @ z1 */                   \
        u32 b1 = (ii1) ? (d).w : (d).y;  /* c2c3 @ z1 */                   \
        float2 fa0 = h2f(a0), fa1 = h2f(a1);                               \
        float2 fb0 = h2f(b0), fb1 = h2f(b1);                               \
        ox += (wA) * fa0.x + (wB) * fb0.x;                                 \
        oy += (wA) * fa0.y + (wB) * fb0.y;                                 \
        oz += (wA) * fa1.x + (wB) * fb1.x;                                 \
        ow += (wA) * fa1.y + (wB) * fb1.y;                                 \
    }

#define FINISH(S)                                                          \
    {                                                                      \
        float ex = 1.0f - dx##S, ey = 1.0f - dy##S, ez = 1.0f - dz##S;     \
        float wA0 = dz##S * dx##S * dy##S, wB0 = ez * dx##S * dy##S;       \
        float wA1 = dz##S * dx##S * ey,    wB1 = ez * dx##S * ey;          \
        float wA2 = dz##S * ex * dy##S,    wB2 = ez * ex * dy##S;          \
        float wA3 = dz##S * ex * ey,       wB3 = ez * ex * ey;             \
        float ox = 0.f, oy = 0.f, oz = 0.f, ow = 0.f;                      \
        ACC1(d0##S, wA0, wB0, i0##S, i1##S, ox, oy, oz, ow)                \
        ACC1(d1##S, wA1, wB1, i0##S, i1##S, ox, oy, oz, ow)                \
        ACC1(d2##S, wA2, wB2, i0##S, i1##S, ox, oy, oz, ow)                \
        ACC1(d3##S, wA3, wB3, i0##S, i1##S, ox, oy, oz, ow)                \
        f4 o = {ox, oy, oz, ow};                                           \
        __builtin_nontemporal_store(o, &out[idx##S]);                      \
    }

    FINISH(A)
    FINISH(B)

#undef SETUP
#undef GATHER
#undef ACC1
#undef FINISH
}

// ---- Fallback (proven R4 fp32 kernel) if workspace is too small ----
__global__ __launch_bounds__(256) void st3d_kernel(
    const float* __restrict__ img,
    const float* __restrict__ trans,
    f4* __restrict__ out)
{
    int bid = blockIdx.x;
    int q   = bid & 7;
    int n   = bid >> 3;
    int b   = n >> 10;
    int m   = ((n & 1023) << 8) | threadIdx.x;

    int kp = m & 63;
    int jp = (m >> 6) & 63;
    int ip = m >> 12;

    int qi = (q >> 2) & 1;
    int qj = (q >> 1) & 1;
    int qk = q & 1;

    int ipe = qi ? ip : (63 - ip);
    int i = (qi << 6) + ipe;
    int j = (qj << 6) + jp;
    int k = (qk << 6) + kp;

    int idx = (((b << 7) | i) << 14) | (j << 7) | k;

    const float step = 2.0f / 127.0f;
    float gx = -1.0f + step * (float)j;
    float gy = -1.0f + step * (float)i;
    float gz = -1.0f + step * (float)k;

    const float* t = trans + (size_t)idx * 3;
    float tx = __builtin_nontemporal_load(t + 0);
    float ty = __builtin_nontemporal_load(t + 1);
    float tz = __builtin_nontemporal_load(t + 2);

    float x = (tx * gx + 1.0f) * 64.0f;
    float y = (ty * gy + 1.0f) * 64.0f;
    float z = (tz * gz + 1.0f) * 64.0f;

    int x0 = (int)floorf(x);
    int y0 = (int)floorf(y);
    int z0 = (int)floorf(z);
    int x1 = min(max(x0 + 1, 0), 127);
    int y1 = min(max(y0 + 1, 0), 127);
    int z1 = min(max(z0 + 1, 0), 127);
    x0 = min(max(x0, 0), 127);
    y0 = min(max(y0, 0), 127);
    z0 = min(max(z0, 0), 127);

    float dx = (float)x1 - x;
    float dy = (float)y1 - y;
    float dz = (float)z1 - z;
    float ex = 1.0f - dx;
    float ey = 1.0f - dy;
    float ez = 1.0f - dz;

    const f4* img4 = (const f4*)img;
    int bb  = b << 21;
    int ry0 = bb + (y0 << 14);
    int ry1 = bb + (y1 << 14);
    int cx0 = x0 << 7;
    int cx1 = x1 << 7;

    int A0 = ry0 + cx0 + z0;
    int A1 = ry1 + cx0 + z0;
    int A2 = ry0 + cx1 + z0;
    int A3 = ry1 + cx1 + z0;
    int dzi = z1 - z0;

    f4 c000 = img4[A0];
    f4 c100 = img4[A1];
    f4 c010 = img4[A2];
    f4 c110 = img4[A3];
    f4 c001 = img4[A0 + dzi];
    f4 c101 = img4[A1 + dzi];
    f4 c011 = img4[A2 + dzi];
    f4 c111 = img4[A3 + dzi];

    float w000 = dz * dx * dy;
    float w100 = dz * dx * ey;
    float w010 = dz * ex * dy;
    float w110 = dz * ex * ey;
    float w001 = ez * dx * dy;
    float w101 = ez * dx * ey;
    float w011 = ez * ex * dy;
    float w111 = ez * ex * ey;

    f4 o = w000*c000 + w100*c100 + w010*c010 + w110*c110
         + w001*c001 + w101*c101 + w011*c011 + w111*c111;

    __builtin_nontemporal_store(o, &out[idx]);
}

extern "C" void kernel_launch(void* const* d_in, const int* in_sizes, int n_in,
                              void* d_out, int out_size, void* d_ws, size_t ws_size,
                              hipStream_t stream) {
    const float* img   = (const float*)d_in[0];
    const float* trans = (const float*)d_in[1];
    f4* out = (f4*)d_out;

    int N = in_sizes[1] / 3;            // B*128^3 = 4,194,304 voxels
    int block = 256;

    size_t need = (size_t)N * 4 * sizeof(__half);   // 33.5 MB fp16 image
    if (ws_size >= need) {
        cvt_kernel<<<N / block, block, 0, stream>>>((const f4*)img, (uint2*)d_ws);
        st3d_h2_kernel<<<N / (2 * block), block, 0, stream>>>(
            (const u32*)d_ws, trans, out);
    } else {
        st3d_kernel<<<N / block, block, 0, stream>>>(img, trans, out);
    }
}

// Round 2
// 222.107 us; speedup vs baseline: 1.0699x; 1.0436x over previous
//
#include <hip/hip_runtime.h>
#include <hip/hip_fp16.h>

// SpatialTransformer3D: B=2, H=W=D=128, C=4.
// out[b,i,j,k,:] = trilinear sample of image[b] at c = t*grid, t in [0,1).
//
// R8: R7 (2 voxels/thread, 8 gathers in flight) gave only -4% -> pipe is
// throughput-saturated at ~3.7 cy per distinct-line touch, not latency-
// starved. If the saturated unit is L1-miss-initiation or L2 request rate
// (per LINE), touching fewer lines wins; if it's TA address-crack (per
// lane-address), nothing changes. Lever: 4x-duplicated 32B records
// rec[b][y][x][z] = 2x2 (y,x)-corner quad (edge-replicated, fp16) at one z.
// A voxel's 8 corners = one contiguous 64B window at (y0,x0,zb):
// 4 dwordx4 insts (same as now) but 1.5 expected lines/voxel vs 4.
// Octant q -> XCD q map kept. Tiered ws: 134MB records / 33.5MB fp16 / fp32.

typedef float f4 __attribute__((ext_vector_type(4)));
typedef unsigned int u32;
typedef u32 u4v __attribute__((ext_vector_type(4), aligned(8)));

__device__ inline float2 h2f(u32 b) {
    __half2 h = __builtin_bit_cast(__half2, b);
    return __half22float2(h);
}
__device__ inline u32 f2h2(float a, float b) {
    __half2 h = __floats2half2_rn(a, b);
    return __builtin_bit_cast(u32, h);
}

// ---- Pass 1 (tier Q): fp32 image -> 32B (y,x)-corner-quad fp16 records ----
__global__ __launch_bounds__(256) void cvtq_kernel(
    const f4* __restrict__ img, u4v* __restrict__ rec)
{
    int t = blockIdx.x * 256 + threadIdx.x;   // record id = voxel id
    int z = t & 127;
    int x = (t >> 7) & 127;
    int y = (t >> 14) & 127;
    int b = t >> 21;
    int x1 = min(x + 1, 127);                 // edge-replicate (matches
    int y1 = min(y + 1, 127);                 // reference clipped corners)
    int bb = b << 21;

    f4 v00 = img[bb | (y  << 14) | (x  << 7) | z];
    f4 v10 = img[bb | (y1 << 14) | (x  << 7) | z];
    f4 v01 = img[bb | (y  << 14) | (x1 << 7) | z];
    f4 v11 = img[bb | (y1 << 14) | (x1 << 7) | z];

    // record layout: [ (y0,x0) , (y1,x0) | (y0,x1) , (y1,x1) ], 8B each
    u4v r0 = { f2h2(v00.x, v00.y), f2h2(v00.z, v00.w),
               f2h2(v10.x, v10.y), f2h2(v10.z, v10.w) };
    u4v r1 = { f2h2(v01.x, v01.y), f2h2(v01.z, v01.w),
               f2h2(v11.x, v11.y), f2h2(v11.z, v11.w) };
    rec[(size_t)t * 2]     = r0;
    rec[(size_t)t * 2 + 1] = r1;
}

// ---- Pass 2 (tier Q): sample from records, 2 voxels/thread ----
__global__ __launch_bounds__(256) void st3d_q_kernel(
    const u32* __restrict__ rec,       // (B,128,128,128) 32B records
    const float* __restrict__ trans,   // (B,128,128,128,3) fp32
    f4* __restrict__ out)              // (B,128,128,128,4) fp32
{
    int bid = blockIdx.x;
    int q   = bid & 7;                      // octant -> XCD
    int n   = bid >> 3;                     // 0..1023
    int b   = n >> 9;
    int mA  = ((n & 511) << 8) | threadIdx.x;   // ip 0..31
    int mB  = mA + (1 << 17);                   // ip 32..63

    int qi = (q >> 2) & 1;
    int qj = (q >> 1) & 1;
    int qk = q & 1;

    const float step = 2.0f / 127.0f;

#define SETUPQ(S, mval)                                                    \
    int kp##S  = (mval) & 63;                                              \
    int jp##S  = ((mval) >> 6) & 63;                                       \
    int ip##S  = (mval) >> 12;                                             \
    int ipe##S = qi ? ip##S : (63 - ip##S);                                \
    int i##S   = (qi << 6) + ipe##S;                                       \
    int j##S   = (qj << 6) + jp##S;                                        \
    int k##S   = (qk << 6) + kp##S;                                        \
    int idx##S = (((b << 7) | i##S) << 14) | (j##S << 7) | k##S;           \
    const float* t##S = trans + (size_t)idx##S * 3;                        \
    float tx##S = __builtin_nontemporal_load(t##S + 0);                    \
    float ty##S = __builtin_nontemporal_load(t##S + 1);                    \
    float tz##S = __builtin_nontemporal_load(t##S + 2);

    SETUPQ(A, mA)
    SETUPQ(B, mB)

#define GATHERQ(S)                                                         \
    float gx##S = -1.0f + step * (float)j##S;                              \
    float gy##S = -1.0f + step * (float)i##S;                              \
    float gz##S = -1.0f + step * (float)k##S;                              \
    float x##S = (tx##S * gx##S + 1.0f) * 64.0f;                           \
    float y##S = (ty##S * gy##S + 1.0f) * 64.0f;                           \
    float z##S = (tz##S * gz##S + 1.0f) * 64.0f;                           \
    int x0##S = (int)floorf(x##S);                                         \
    int y0##S = (int)floorf(y##S);                                         \
    int z0##S = (int)floorf(z##S);                                         \
    int x1##S = min(max(x0##S + 1, 0), 127);                               \
    int y1##S = min(max(y0##S + 1, 0), 127);                               \
    int z1##S = min(max(z0##S + 1, 0), 127);                               \
    x0##S = min(max(x0##S, 0), 127);                                       \
    y0##S = min(max(y0##S, 0), 127);                                       \
    z0##S = min(max(z0##S, 0), 127);                                       \
    /* weights use CLIPPED upper corners (reference semantics) */          \
    float dx##S = (float)x1##S - x##S;                                     \
    float dy##S = (float)y1##S - y##S;                                     \
    float dz##S = (float)z1##S - z##S;                                     \
    int zb##S = min(z0##S, 126);        /* window = records zb, zb+1 */    \
    int i0##S = z0##S - zb##S;          /* 0 normally; 1 when z0==127 */   \
    int i1##S = z1##S - zb##S;          /* 1 normally */                   \
    int r##S = (((b << 7) | y0##S) << 14) | (x0##S << 7) | zb##S;          \
    const u4v* p##S = (const u4v*)(rec + (size_t)r##S * 8);                \
    u4v L0##S = p##S[0];   /* (y0,x0),(y1,x0) @ zb   */                    \
    u4v L1##S = p##S[1];   /* (y0,x1),(y1,x1) @ zb   */                    \
    u4v L2##S = p##S[2];   /* (y0,x0),(y1,x0) @ zb+1 */                    \
    u4v L3##S = p##S[3];   /* (y0,x1),(y1,x1) @ zb+1 */

    GATHERQ(A)
    GATHERQ(B)

#define ACCQ(lo0, lo1, hi0, hi1, wA, wB)                                   \
    {                                                                      \
        u32 a0 = i0s ? (hi0) : (lo0);   /* c0c1 @ z0 */                    \
        u32 a1 = i0s ? (hi1) : (lo1);   /* c2c3 @ z0 */                    \
        u32 b0 = i1s ? (hi0) : (lo0);   /* c0c1 @ z1 */                    \
        u32 b1 = i1s ? (hi1) : (lo1);   /* c2c3 @ z1 */                    \
        float2 fa0 = h2f(a0), fa1 = h2f(a1);                               \
        float2 fb0 = h2f(b0), fb1 = h2f(b1);                               \
        ox += (wA) * fa0.x + (wB) * fb0.x;                                 \
        oy += (wA) * fa0.y + (wB) * fb0.y;                                 \
        oz += (wA) * fa1.x + (wB) * fb1.x;                                 \
        ow += (wA) * fa1.y + (wB) * fb1.y;                                 \
    }

#define FINISHQ(S)                                                         \
    {                                                                      \
        float ex = 1.0f - dx##S, ey = 1.0f - dy##S, ez = 1.0f - dz##S;     \
        float wA0 = dz##S * dx##S * dy##S, wB0 = ez * dx##S * dy##S;       \
        float wA1 = dz##S * dx##S * ey,    wB1 = ez * dx##S * ey;          \
        float wA2 = dz##S * ex * dy##S,    wB2 = ez * ex * dy##S;          \
        float wA3 = dz##S * ex * ey,       wB3 = ez * ex * ey;             \
        int i0s = i0##S, i1s = i1##S;                                      \
        float ox = 0.f, oy = 0.f, oz = 0.f, ow = 0.f;                      \
        ACCQ(L0##S.x, L0##S.y, L2##S.x, L2##S.y, wA0, wB0)  /* (y0,x0) */  \
        ACCQ(L0##S.z, L0##S.w, L2##S.z, L2##S.w, wA1, wB1)  /* (y1,x0) */  \
        ACCQ(L1##S.x, L1##S.y, L3##S.x, L3##S.y, wA2, wB2)  /* (y0,x1) */  \
        ACCQ(L1##S.z, L1##S.w, L3##S.z, L3##S.w, wA3, wB3)  /* (y1,x1) */  \
        f4 o = {ox, oy, oz, ow};                                           \
        __builtin_nontemporal_store(o, &out[idx##S]);                      \
    }

    FINISHQ(A)
    FINISHQ(B)

#undef SETUPQ
#undef GATHERQ
#undef ACCQ
#undef FINISHQ
}

// ---- Tier H (proven R7): fp16 plain copy ----
__global__ __launch_bounds__(256) void cvt_kernel(
    const f4* __restrict__ img, uint2* __restrict__ himg)
{
    int idx = blockIdx.x * 256 + threadIdx.x;
    f4 v = img[idx];
    __half2 lo = __floats2half2_rn(v.x, v.y);
    __half2 hi = __floats2half2_rn(v.z, v.w);
    himg[idx] = make_uint2(__builtin_bit_cast(u32, lo), __builtin_bit_cast(u32, hi));
}

__global__ __launch_bounds__(256) void st3d_h_kernel(
    const u32* __restrict__ himg,
    const float* __restrict__ trans,
    f4* __restrict__ out)
{
    int bid = blockIdx.x;
    int q   = bid & 7;
    int n   = bid >> 3;
    int b   = n >> 10;
    int m   = ((n & 1023) << 8) | threadIdx.x;

    int kp = m & 63;
    int jp = (m >> 6) & 63;
    int ip = m >> 12;

    int qi = (q >> 2) & 1;
    int qj = (q >> 1) & 1;
    int qk = q & 1;

    int ipe = qi ? ip : (63 - ip);
    int i = (qi << 6) + ipe;
    int j = (qj << 6) + jp;
    int k = (qk << 6) + kp;

    int idx = (((b << 7) | i) << 14) | (j << 7) | k;

    const float step = 2.0f / 127.0f;
    float gx = -1.0f + step * (float)j;
    float gy = -1.0f + step * (float)i;
    float gz = -1.0f + step * (float)k;

    const float* t = trans + (size_t)idx * 3;
    float tx = __builtin_nontemporal_load(t + 0);
    float ty = __builtin_nontemporal_load(t + 1);
    float tz = __builtin_nontemporal_load(t + 2);

    float x = (tx * gx + 1.0f) * 64.0f;
    float y = (ty * gy + 1.0f) * 64.0f;
    float z = (tz * gz + 1.0f) * 64.0f;

    int x0 = (int)floorf(x);
    int y0 = (int)floorf(y);
    int z0 = (int)floorf(z);
    int x1 = min(max(x0 + 1, 0), 127);
    int y1 = min(max(y0 + 1, 0), 127);
    int z1 = min(max(z0 + 1, 0), 127);
    x0 = min(max(x0, 0), 127);
    y0 = min(max(y0, 0), 127);
    z0 = min(max(z0, 0), 127);

    float dx = (float)x1 - x;
    float dy = (float)y1 - y;
    float dz = (float)z1 - z;
    float ex = 1.0f - dx;
    float ey = 1.0f - dy;
    float ez = 1.0f - dz;

    int zb = min(z0, 126);
    int i0 = z0 - zb;
    int i1 = z1 - zb;

    int bb  = b << 21;
    int ry0 = bb + (y0 << 14);
    int ry1 = bb + (y1 << 14);
    int cx0 = x0 << 7;
    int cx1 = x1 << 7;

    const u4v* p0 = (const u4v*)(himg + (size_t)(ry0 + cx0 + zb) * 2);
    const u4v* p1 = (const u4v*)(himg + (size_t)(ry1 + cx0 + zb) * 2);
    const u4v* p2 = (const u4v*)(himg + (size_t)(ry0 + cx1 + zb) * 2);
    const u4v* p3 = (const u4v*)(himg + (size_t)(ry1 + cx1 + zb) * 2);

    u4v d0 = *p0;
    u4v d1 = *p1;
    u4v d2 = *p2;
    u4v d3 = *p3;

    float wA0 = dz * dx * dy, wB0 = ez * dx * dy;
    float wA1 = dz * dx * ey, wB1 = ez * dx * ey;
    float wA2 = dz * ex * dy, wB2 = ez * ex * dy;
    float wA3 = dz * ex * ey, wB3 = ez * ex * ey;

    float ox = 0.f, oy = 0.f, oz = 0.f, ow = 0.f;

#define ACC(d, wA, wB)                                            \
    {                                                             \
        u32 a0 = i0 ? (d).z : (d).x;                              \
        u32 a1 = i0 ? (d).w : (d).y;                              \
        u32 b0 = i1 ? (d).z : (d).x;                              \
        u32 b1 = i1 ? (d).w : (d).y;                              \
        float2 fa0 = h2f(a0), fa1 = h2f(a1);                      \
        float2 fb0 = h2f(b0), fb1 = h2f(b1);                      \
        ox += (wA) * fa0.x + (wB) * fb0.x;                        \
        oy += (wA) * fa0.y + (wB) * fb0.y;                        \
        oz += (wA) * fa1.x + (wB) * fb1.x;                        \
        ow += (wA) * fa1.y + (wB) * fb1.y;                        \
    }

    ACC(d0, wA0, wB0)
    ACC(d1, wA1, wB1)
    ACC(d2, wA2, wB2)
    ACC(d3, wA3, wB3)
#undef ACC

    f4 o = {ox, oy, oz, ow};
    __builtin_nontemporal_store(o, &out[idx]);
}

// ---- Tier F (proven R4 fp32) ----
__global__ __launch_bounds__(256) void st3d_kernel(
    const float* __restrict__ img,
    const float* __restrict__ trans,
    f4* __restrict__ out)
{
    int bid = blockIdx.x;
    int q   = bid & 7;
    int n   = bid >> 3;
    int b   = n >> 10;
    int m   = ((n & 1023) << 8) | threadIdx.x;

    int kp = m & 63;
    int jp = (m >> 6) & 63;
    int ip = m >> 12;

    int qi = (q >> 2) & 1;
    int qj = (q >> 1) & 1;
    int qk = q & 1;

    int ipe = qi ? ip : (63 - ip);
    int i = (qi << 6) + ipe;
    int j = (qj << 6) + jp;
    int k = (qk << 6) + kp;

    int idx = (((b << 7) | i) << 14) | (j << 7) | k;

    const float step = 2.0f / 127.0f;
    float gx = -1.0f + step * (float)j;
    float gy = -1.0f + step * (float)i;
    float gz = -1.0f + step * (float)k;

    const float* t = trans + (size_t)idx * 3;
    float tx = __builtin_nontemporal_load(t + 0);
    float ty = __builtin_nontemporal_load(t + 1);
    float tz = __builtin_nontemporal_load(t + 2);

    float x = (tx * gx + 1.0f) * 64.0f;
    float y = (ty * gy + 1.0f) * 64.0f;
    float z = (tz * gz + 1.0f) * 64.0f;

    int x0 = (int)floorf(x);
    int y0 = (int)floorf(y);
    int z0 = (int)floorf(z);
    int x1 = min(max(x0 + 1, 0), 127);
    int y1 = min(max(y0 + 1, 0), 127);
    int z1 = min(max(z0 + 1, 0), 127);
    x0 = min(max(x0, 0), 127);
    y0 = min(max(y0, 0), 127);
    z0 = min(max(z0, 0), 127);

    float dx = (float)x1 - x;
    float dy = (float)y1 - y;
    float dz = (float)z1 - z;
    float ex = 1.0f - dx;
    float ey = 1.0f - dy;
    float ez = 1.0f - dz;

    const f4* img4 = (const f4*)img;
    int bb  = b << 21;
    int ry0 = bb + (y0 << 14);
    int ry1 = bb + (y1 << 14);
    int cx0 = x0 << 7;
    int cx1 = x1 << 7;

    int A0 = ry0 + cx0 + z0;
    int A1 = ry1 + cx0 + z0;
    int A2 = ry0 + cx1 + z0;
    int A3 = ry1 + cx1 + z0;
    int dzi = z1 - z0;

    f4 c000 = img4[A0];
    f4 c100 = img4[A1];
    f4 c010 = img4[A2];
    f4 c110 = img4[A3];
    f4 c001 = img4[A0 + dzi];
    f4 c101 = img4[A1 + dzi];
    f4 c011 = img4[A2 + dzi];
    f4 c111 = img4[A3 + dzi];

    float w000 = dz * dx * dy;
    float w100 = dz * dx * ey;
    float w010 = dz * ex * dy;
    float w110 = dz * ex * ey;
    float w001 = ez * dx * dy;
    float w101 = ez * dx * ey;
    float w011 = ez * ex * dy;
    float w111 = ez * ex * ey;

    f4 o = w000*c000 + w100*c100 + w010*c010 + w110*c110
         + w001*c001 + w101*c101 + w011*c011 + w111*c111;

    __builtin_nontemporal_store(o, &out[idx]);
}

extern "C" void kernel_launch(void* const* d_in, const int* in_sizes, int n_in,
                              void* d_out, int out_size, void* d_ws, size_t ws_size,
                              hipStream_t stream) {
    const float* img   = (const float*)d_in[0];
    const float* trans = (const float*)d_in[1];
    f4* out = (f4*)d_out;

    int N = in_sizes[1] / 3;            // B*128^3 = 4,194,304 voxels
    int block = 256;

    size_t need_q = (size_t)N * 32;     // 134 MB corner-quad records
    size_t need_h = (size_t)N * 8;      // 33.5 MB fp16 image

    if (ws_size >= need_q) {
        cvtq_kernel<<<N / block, block, 0, stream>>>((const f4*)img, (u4v*)d_ws);
        st3d_q_kernel<<<N / (2 * block), block, 0, stream>>>(
            (const u32*)d_ws, trans, out);
    } else if (ws_size >= need_h) {
        cvt_kernel<<<N / block, block, 0, stream>>>((const f4*)img, (uint2*)d_ws);
        st3d_h_kernel<<<N / block, block, 0, stream>>>(
            (const u32*)d_ws, trans, out);
    } else {
        st3d_kernel<<<N / block, block, 0, stream>>>(img, trans, out);
    }
}